// Round 4
// baseline (2278.613 us; speedup 1.0000x reference)
//
#include <hip/hip_runtime.h>

// ResidualQuantizer: K=4 stages, C=1024 centroids, D=64, N=B*T=131072 rows.
// Outputs (flat f32 concat): quantized[N*D], loss[N], nn_idx[K*N] (as float),
// codebooks_out[K*C*D], counts[K*C].
//
// Strategy: bit-match the checker's numpy-f32 reference pipeline:
//  - dot(residual, centroid): single sequential k-ascending f32 FMA chain
//    (BLAS sgemm microkernel order)
//  - ||c||^2: numpy pairwise-8 sum of separately-rounded squares
//  - score = fmaf(-2, dot, cn)  (== fl(-2*dot + cn), -2* is exact)
//  - argmin: first strict min, ascending c
//  - STE/residual updates in reference f32 op order

#define RQ_K 4
#define RQ_C 1024
#define RQ_D 64
#define RQ_N 131072

// ---------------- kernel 0: centroid norms, numpy pairwise-8 order ----------------
__global__ void rq_cnorm_kernel(const float* __restrict__ cb,
                                float* __restrict__ cn32) {
  int c = blockIdx.x * blockDim.x + threadIdx.x;
  if (c >= RQ_K * RQ_C) return;
  const float* p = cb + (size_t)c * RQ_D;
  float rr[8];
#pragma unroll
  for (int j = 0; j < 8; ++j) {
    float sq = p[j] * p[j];
    asm volatile("" : "+v"(sq));  // forbid fma contraction: square rounds alone
    rr[j] = sq;
  }
#pragma unroll
  for (int i = 8; i < RQ_D; i += 8) {
#pragma unroll
    for (int j = 0; j < 8; ++j) {
      float sq = p[i + j] * p[i + j];
      asm volatile("" : "+v"(sq));
      rr[j] = rr[j] + sq;
    }
  }
  float s = ((rr[0] + rr[1]) + (rr[2] + rr[3])) + ((rr[4] + rr[5]) + (rr[6] + rr[7]));
  cn32[c] = s;
}

// ---------------- kernel 1: main RQ (one row per lane) ----------------
__launch_bounds__(256, 2)
__global__ void rq_main_kernel(const float* __restrict__ in,
                               const float* __restrict__ cb,
                               const float* __restrict__ cn32,
                               float* __restrict__ out_q,
                               float* __restrict__ out_nn,
                               float* __restrict__ out_counts,
                               double* __restrict__ ssq_acc) {
  const int row = blockIdx.x * blockDim.x + threadIdx.x;  // exact grid: 0..N-1

  float r[RQ_D];     // current residual (f32, reference rounding)
  float qsum[RQ_D];  // running sum of quant_ste over stages
  {
    const float4* ip = reinterpret_cast<const float4*>(in + (size_t)row * RQ_D);
#pragma unroll
    for (int i = 0; i < RQ_D / 4; ++i) {
      float4 v = ip[i];
      r[4 * i + 0] = v.x; r[4 * i + 1] = v.y;
      r[4 * i + 2] = v.z; r[4 * i + 3] = v.w;
      qsum[4 * i + 0] = 0.f; qsum[4 * i + 1] = 0.f;
      qsum[4 * i + 2] = 0.f; qsum[4 * i + 3] = 0.f;
    }
  }
  double ssq = 0.0;  // loss partial

#pragma unroll 1
  for (int k = 0; k < RQ_K; ++k) {
    const float* cbk = cb + (size_t)k * RQ_C * RQ_D;
    const float* cnk = cn32 + k * RQ_C;
    float m1 = 3.402823466e38f;
    int i1 = 0;

    // f32 screening, 4 centroids per iteration (4 independent chains; each
    // chain is the sequential k-ascending FMA order numpy's sgemm uses).
#pragma unroll 1
    for (int c = 0; c < RQ_C; c += 4) {
      const float4* b0 = reinterpret_cast<const float4*>(cbk + (size_t)(c + 0) * RQ_D);
      const float4* b1 = reinterpret_cast<const float4*>(cbk + (size_t)(c + 1) * RQ_D);
      const float4* b2 = reinterpret_cast<const float4*>(cbk + (size_t)(c + 2) * RQ_D);
      const float4* b3 = reinterpret_cast<const float4*>(cbk + (size_t)(c + 3) * RQ_D);
      float a0 = 0.f, a1 = 0.f, a2 = 0.f, a3 = 0.f;
#pragma unroll
      for (int i = 0; i < RQ_D / 4; ++i) {
        float4 v0 = b0[i];
        a0 = fmaf(v0.x, r[4 * i + 0], a0);
        a0 = fmaf(v0.y, r[4 * i + 1], a0);
        a0 = fmaf(v0.z, r[4 * i + 2], a0);
        a0 = fmaf(v0.w, r[4 * i + 3], a0);
        float4 v1 = b1[i];
        a1 = fmaf(v1.x, r[4 * i + 0], a1);
        a1 = fmaf(v1.y, r[4 * i + 1], a1);
        a1 = fmaf(v1.z, r[4 * i + 2], a1);
        a1 = fmaf(v1.w, r[4 * i + 3], a1);
        float4 v2 = b2[i];
        a2 = fmaf(v2.x, r[4 * i + 0], a2);
        a2 = fmaf(v2.y, r[4 * i + 1], a2);
        a2 = fmaf(v2.z, r[4 * i + 2], a2);
        a2 = fmaf(v2.w, r[4 * i + 3], a2);
        float4 v3 = b3[i];
        a3 = fmaf(v3.x, r[4 * i + 0], a3);
        a3 = fmaf(v3.y, r[4 * i + 1], a3);
        a3 = fmaf(v3.z, r[4 * i + 2], a3);
        a3 = fmaf(v3.w, r[4 * i + 3], a3);
      }
      // score = fl(-2*dot + cn); -2*dot is exact (power-of-2 scale)
      float s0 = fmaf(-2.f, a0, cnk[c + 0]);
      float s1 = fmaf(-2.f, a1, cnk[c + 1]);
      float s2 = fmaf(-2.f, a2, cnk[c + 2]);
      float s3 = fmaf(-2.f, a3, cnk[c + 3]);
      // first-strict-min, ascending c (numpy argmin semantics)
      bool l0 = s0 < m1; m1 = l0 ? s0 : m1; i1 = l0 ? (c + 0) : i1;
      bool l1 = s1 < m1; m1 = l1 ? s1 : m1; i1 = l1 ? (c + 1) : i1;
      bool l2 = s2 < m1; m1 = l2 ? s2 : m1; i1 = l2 ? (c + 2) : i1;
      bool l3 = s3 < m1; m1 = l3 ? s3 : m1; i1 = l3 ? (c + 3) : i1;
    }

    const int best = i1;
    out_nn[k * RQ_N + row] = (float)best;
    atomicAdd(&out_counts[k * RQ_C + best], 1.0f);

    // residual / STE update, reference f32 op order
    const float4* qp = reinterpret_cast<const float4*>(cbk + (size_t)best * RQ_D);
#pragma unroll
    for (int i = 0; i < RQ_D / 4; ++i) {
      float4 qv = qp[i];
      float qa[4] = {qv.x, qv.y, qv.z, qv.w};
#pragma unroll
      for (int j = 0; j < 4; ++j) {
        int d = 4 * i + j;
        float t = qa[j] - r[d];   // quant - residual
        float qste = r[d] + t;    // straight-through value
        qsum[d] += qste;          // stage-ascending sum, matches np axis-0 sum (n=4 sequential)
        r[d] = r[d] - qste;       // new residual
        ssq = fma((double)t, (double)t, ssq);
      }
    }
  }

  // write quantized
  {
    float4* op = reinterpret_cast<float4*>(out_q + (size_t)row * RQ_D);
#pragma unroll
    for (int i = 0; i < RQ_D / 4; ++i) {
      op[i] = make_float4(qsum[4 * i + 0], qsum[4 * i + 1],
                          qsum[4 * i + 2], qsum[4 * i + 3]);
    }
  }

  // block-reduce loss partial (double), one atomic per block
#pragma unroll
  for (int off = 32; off > 0; off >>= 1) ssq += __shfl_down(ssq, off);
  __shared__ double smem[4];
  int lane = threadIdx.x & 63;
  int wid = threadIdx.x >> 6;
  if (lane == 0) smem[wid] = ssq;
  __syncthreads();
  if (threadIdx.x == 0) {
    double t = (smem[0] + smem[1]) + (smem[2] + smem[3]);
    atomicAdd(ssq_acc, t);
  }
}

// ---------------- kernel 2: loss broadcast + codebook copy ----------------
__global__ void rq_final_kernel(const double* __restrict__ ssq_acc,
                                const float* __restrict__ cb,
                                float* __restrict__ out_loss,
                                float* __restrict__ out_cb) {
  int i = blockIdx.x * blockDim.x + threadIdx.x;
  float lossf = (float)(ssq_acc[0] / (double)((long long)RQ_N * RQ_D));
  if (i < RQ_N) out_loss[i] = lossf;
  if (i < RQ_K * RQ_C * RQ_D) out_cb[i] = cb[i];
}

extern "C" void kernel_launch(void* const* d_in, const int* in_sizes, int n_in,
                              void* d_out, int out_size, void* d_ws, size_t ws_size,
                              hipStream_t stream) {
  const float* in = (const float*)d_in[0];
  const float* cb = (const float*)d_in[1];
  float* out = (float*)d_out;

  float* out_q      = out;                       // 8388608
  float* out_loss   = out + 8388608;             // 131072
  float* out_nn     = out + 8519680;             // 524288
  float* out_cb     = out + 9043968;             // 262144
  float* out_counts = out + 9306112;             // 4096  (total 9310208)

  double* ws_ssq = (double*)d_ws;
  float*  cn32   = (float*)((char*)d_ws + 16);

  hipMemsetAsync(d_ws, 0, 16, stream);
  hipMemsetAsync(out_counts, 0, RQ_K * RQ_C * sizeof(float), stream);

  rq_cnorm_kernel<<<(RQ_K * RQ_C) / 256, 256, 0, stream>>>(cb, cn32);
  rq_main_kernel<<<RQ_N / 256, 256, 0, stream>>>(in, cb, cn32,
                                                 out_q, out_nn, out_counts, ws_ssq);
  rq_final_kernel<<<(RQ_K * RQ_C * RQ_D) / 256, 256, 0, stream>>>(ws_ssq, cb,
                                                                  out_loss, out_cb);
}